// Round 6
// baseline (381.396 us; speedup 1.0000x reference)
//
#include <hip/hip_runtime.h>
#include <stdint.h>
#include <math.h>

#define T_TOK 512
#define DDIM  2048
#define IDIM  768
#define NEXP  16
#define TOPK  8
#define LDB   72   // LDS B row stride (bf16 units)

typedef __attribute__((ext_vector_type(8))) short bf16x8;
typedef __attribute__((ext_vector_type(4))) float f32x4;

// ---------- fp8 e4m3fn RTNE quant-dequant (fp32-exact, result fits bf16) ----------
__device__ __forceinline__ float e4m3_rtne(float f) {
  uint32_t u = __float_as_uint(f);
  uint32_t sign = u & 0x80000000u;
  uint32_t a = u & 0x7FFFFFFFu;
  float fa = __uint_as_float(a);
  float out;
  if (fa >= 0.015625f) {            // normal: keep 3 mantissa bits, RTNE
    uint32_t lsb = (a >> 20) & 1u;
    a += 0x0007FFFFu + lsb;
    a &= 0xFFF00000u;
    out = __uint_as_float(a);
  } else {                          // subnormal: quantum 2^-9
    out = rintf(fa * 512.0f) * 0.001953125f;
  }
  return __uint_as_float(__float_as_uint(out) | sign);
}

__global__ void qdq_kernel(const float* __restrict__ x, ushort* __restrict__ xq) {
  int idx = blockIdx.x * 256 + threadIdx.x;
  float v = x[idx];
  float a = fabsf(v);
#pragma unroll
  for (int m = 16; m >= 1; m >>= 1)
    a = fmaxf(a, __shfl_xor(a, m, 32));
  a = fmaxf(a, 1e-4f);
  float scale = a / 448.0f;
  uint32_t b = __float_as_uint(scale);
  uint32_t ex = ((b >> 23) & 255u) + ((b & 0x7FFFFFu) ? 1u : 0u);
  ex = ex < 1u ? 1u : (ex > 254u ? 254u : ex);
  float rscale = __uint_as_float(ex << 23);
  float inv = 1.0f / rscale;
  float r = e4m3_rtne(v * inv) * rscale;       // exactly representable in bf16
  xq[idx] = (ushort)(__float_as_uint(r) >> 16);
}

// ---------- routing ----------
__global__ void route_kernel(const int* __restrict__ ids, const float* __restrict__ wts,
                             int* counts, int* offsets, int* lists, float* combs,
                             int* tpe, int* tps, int* tpn) {
  int t = threadIdx.x;  // 512 threads
  int  myid[TOPK];
  float myw[TOPK];
#pragma unroll
  for (int k = 0; k < TOPK; k++) { myid[k] = ids[t*TOPK+k]; myw[k] = wts[t*TOPK+k]; }
  int np = 0;
  for (int e = 0; e < NEXP; e++) {
    float s = 0.f; bool r = false;
#pragma unroll
    for (int k = 0; k < TOPK; k++) if (myid[k] == e) { s += myw[k]; r = true; }
    if (r) {
      int slot = atomicAdd(&counts[e], 1);
      lists[(e<<9) + slot] = t;
      combs[(e<<9) + slot] = s;
      tpe[t*TOPK + np] = e;
      tps[t*TOPK + np] = slot;
      np++;
    }
  }
  tpn[t] = np;
  __syncthreads();
  if (t == 0) {
    int acc = 0;
    for (int e = 0; e < NEXP; e++) {
      offsets[e] = acc;
      acc += atomicAdd(&counts[e], 0);
    }
    offsets[NEXP] = acc;
  }
}

// ---------- fp4 int (1 byte payload) -> packed 2x bf16; S = (sf-1)<<1 ----------
__device__ __forceinline__ uint32_t dec2(uint32_t w8, uint32_t S) {
  uint32_t lo = w8 & 15u, hi = (w8 >> 4) & 15u;
  uint32_t mlo = lo & 7u, mhi = hi & 7u;
  uint32_t clo = (mlo < 2u) ? 0u : mlo;
  uint32_t chi = (mhi < 2u) ? 0u : mhi;
  uint32_t blo = (mlo == 0u) ? 0u : ((S + clo) << 6);
  uint32_t bhi = (mhi == 0u) ? 0u : ((S + chi) << 6);
  blo |= (lo & 8u) << 12;
  bhi |= (hi & 8u) << 12;
  return blo | (bhi << 16);
}

// ---------- GEMM1: M=128 (4 waves x 32), N=16 i-cols (gate+up), BK=64, pipelined ----------
__global__ __launch_bounds__(256,4) void gemm1_kernel(
    const ushort* __restrict__ xq, const int* __restrict__ w13,
    const int* __restrict__ w13s, const int* __restrict__ counts,
    const int* __restrict__ offsets, const int* __restrict__ lists,
    const float* __restrict__ combs, ushort* __restrict__ a_buf)
{
  const int e  = blockIdx.x;
  const int i0 = blockIdx.y << 4;     // 16 feature cols
  const int m0 = blockIdx.z << 7;     // 128 token rows
  const int cnt = counts[e];
  if (m0 >= cnt) return;

  __shared__ __align__(16) ushort Bsh[2][32*LDB];   // 2 x 4.5 KB (16 gate rows + 16 up rows)
  __shared__ int   toks[128];
  __shared__ float cmbs[128];

  const int tid = threadIdx.x;
  if (tid < 128) {
    int m = m0 + tid; bool v = m < cnt;
    toks[tid] = v ? lists[(e<<9)+m] : 0;
    cmbs[tid] = v ? combs[(e<<9)+m] : 0.f;
  }
  __syncthreads();

  const int wv = tid >> 6, l = tid & 63, l16 = l & 15, q = l >> 4;

  // A sources: wave wv covers rows wv*32 + i*16 + l16, i<2; k-offset q*8 within 32-chunk
  const ushort* arow[2];
#pragma unroll
  for (int i = 0; i < 2; i++)
    arow[i] = xq + (size_t)toks[wv*32 + i*16 + l16]*DDIM + q*8;

  // B staging: 32 rows (16 gate + 16 up) x 64 k per iter; 8 threads/row, 1 chunk (8 k = int4) each
  const int rb = tid >> 3, ck = tid & 7;
  const int feat = (rb < 16) ? (i0 + rb) : (IDIM + i0 + (rb - 16));
  const int* wrow = w13 + ((size_t)e*(2*IDIM) + feat)*(DDIM/2) + ck*4;
  const int* srow = w13s + ((size_t)e*(2*IDIM) + feat)*(DDIM/32) + (ck >> 2);
  const int bdst = rb*LDB + ck*8;

  f32x4 acc[2][2];
#pragma unroll
  for (int i = 0; i < 2; i++)
#pragma unroll
    for (int j = 0; j < 2; j++) acc[i][j] = (f32x4){0.f,0.f,0.f,0.f};

  // ---- prologue: load + dequant iter 0 ----
  bf16x8 afr[2][2];
#pragma unroll
  for (int i = 0; i < 2; i++)
#pragma unroll
    for (int s = 0; s < 2; s++)
      afr[i][s] = *(const bf16x8*)(arow[i] + s*32);
  {
    int4 w0 = *(const int4*)(wrow);
    uint32_t S = (((uint32_t)srow[0]) - 1u) << 1;
    ushort* d = &Bsh[0][bdst];
    *(uint4*)d = make_uint4(dec2((uint32_t)w0.x, S), dec2((uint32_t)w0.y, S),
                            dec2((uint32_t)w0.z, S), dec2((uint32_t)w0.w, S));
  }
  __syncthreads();

  for (int k0 = 0; k0 < DDIM; k0 += 64) {
    const int cur = (k0 >> 6) & 1;
    const bool more = (k0 + 64) < DDIM;

    // issue next iter's global loads
    int4 nw; uint32_t nS = 0;
    bf16x8 nafr[2][2];
    if (more) {
      nw = *(const int4*)(wrow + ((k0 + 64) >> 1));
      nS = (((uint32_t)srow[(k0 + 64) >> 5]) - 1u) << 1;
#pragma unroll
      for (int i = 0; i < 2; i++)
#pragma unroll
        for (int s = 0; s < 2; s++)
          nafr[i][s] = *(const bf16x8*)(arow[i] + k0 + 64 + s*32);
    }

    // compute current iter
#pragma unroll
    for (int s = 0; s < 2; s++) {
      bf16x8 bfr[2];
#pragma unroll
      for (int j = 0; j < 2; j++)
        bfr[j] = *(const bf16x8*)&Bsh[cur][(j*16 + l16)*LDB + s*32 + q*8];
#pragma unroll
      for (int i = 0; i < 2; i++)
#pragma unroll
        for (int j = 0; j < 2; j++)
          acc[i][j] = __builtin_amdgcn_mfma_f32_16x16x32_bf16(afr[i][s], bfr[j], acc[i][j], 0, 0, 0);
    }

    // dequant next into the other buffer
    if (more) {
      ushort* d = &Bsh[1 - cur][bdst];
      *(uint4*)d = make_uint4(dec2((uint32_t)nw.x, nS), dec2((uint32_t)nw.y, nS),
                              dec2((uint32_t)nw.z, nS), dec2((uint32_t)nw.w, nS));
#pragma unroll
      for (int i = 0; i < 2; i++)
#pragma unroll
        for (int s = 0; s < 2; s++)
          afr[i][s] = nafr[i][s];
    }
    __syncthreads();
  }

  const int obase = offsets[e];
#pragma unroll
  for (int i = 0; i < 2; i++) {
#pragma unroll
    for (int r = 0; r < 4; r++) {
      int mrow = wv*32 + i*16 + q*4 + r;   // C/D: row=(lane>>4)*4+reg, col=lane&15
      int gm = m0 + mrow;
      if (gm < cnt) {
        float c = cmbs[mrow];
        float g = acc[i][0][r], u = acc[i][1][r];
        float val = (g / (1.f + expf(-g))) * u * c;   // comb folded (linear downstream)
        uint32_t bb = __float_as_uint(val);
        bb += 0x7FFFu + ((bb >> 16) & 1u);            // RTNE to bf16
        a_buf[(size_t)(obase + gm)*IDIM + i0 + l16] = (ushort)(bb >> 16);
      }
    }
  }
}

// ---------- GEMM2: M=128 (4 waves x 32), N=32 d-cols, BK=64, pipelined ----------
__global__ __launch_bounds__(256,4) void gemm2_kernel(
    const ushort* __restrict__ a_buf, const int* __restrict__ w2,
    const int* __restrict__ w2s, const int* __restrict__ counts,
    const int* __restrict__ offsets, const int* __restrict__ lists,
    float* __restrict__ out, ushort* __restrict__ ye, int use_ye)
{
  const int e  = blockIdx.x;
  const int n0 = blockIdx.y << 5;     // 32 output cols
  const int m0 = blockIdx.z << 7;     // 128 rows
  const int cnt = counts[e];
  if (m0 >= cnt) return;

  __shared__ __align__(16) ushort Bsh[2][32*LDB];
  __shared__ int toks[128];

  const int tid = threadIdx.x;
  if (tid < 128) {
    int m = m0 + tid;
    toks[tid] = (m < cnt) ? lists[(e<<9)+m] : -1;
  }
  __syncthreads();

  const int wv = tid >> 6, l = tid & 63, l16 = l & 15, q = l >> 4;
  const int obase = offsets[e];

  const ushort* arow[2];
#pragma unroll
  for (int i = 0; i < 2; i++) {
    int gm = m0 + wv*32 + i*16 + l16;
    int rowc = (gm < cnt) ? gm : 0;
    arow[i] = a_buf + (size_t)(obase + rowc)*IDIM + q*8;
  }

  const int rb = tid >> 3, ck = tid & 7;
  const int* wrow = w2 + ((size_t)e*DDIM + n0 + rb)*(IDIM/2) + ck*4;
  const int* srow = w2s + ((size_t)e*DDIM + n0 + rb)*(IDIM/32) + (ck >> 2);
  const int bdst = rb*LDB + ck*8;

  f32x4 acc[2][2];
#pragma unroll
  for (int i = 0; i < 2; i++)
#pragma unroll
    for (int j = 0; j < 2; j++) acc[i][j] = (f32x4){0.f,0.f,0.f,0.f};

  bf16x8 afr[2][2];
#pragma unroll
  for (int i = 0; i < 2; i++)
#pragma unroll
    for (int s = 0; s < 2; s++)
      afr[i][s] = *(const bf16x8*)(arow[i] + s*32);
  {
    int4 w0 = *(const int4*)(wrow);
    uint32_t S = (((uint32_t)srow[0]) - 1u) << 1;
    ushort* d = &Bsh[0][bdst];
    *(uint4*)d = make_uint4(dec2((uint32_t)w0.x, S), dec2((uint32_t)w0.y, S),
                            dec2((uint32_t)w0.z, S), dec2((uint32_t)w0.w, S));
  }
  __syncthreads();

  for (int k0 = 0; k0 < IDIM; k0 += 64) {
    const int cur = (k0 >> 6) & 1;
    const bool more = (k0 + 64) < IDIM;

    int4 nw; uint32_t nS = 0;
    bf16x8 nafr[2][2];
    if (more) {
      nw = *(const int4*)(wrow + ((k0 + 64) >> 1));
      nS = (((uint32_t)srow[(k0 + 64) >> 5]) - 1u) << 1;
#pragma unroll
      for (int i = 0; i < 2; i++)
#pragma unroll
        for (int s = 0; s < 2; s++)
          nafr[i][s] = *(const bf16x8*)(arow[i] + k0 + 64 + s*32);
    }

#pragma unroll
    for (int s = 0; s < 2; s++) {
      bf16x8 bfr[2];
#pragma unroll
      for (int j = 0; j < 2; j++)
        bfr[j] = *(const bf16x8*)&Bsh[cur][(j*16 + l16)*LDB + s*32 + q*8];
#pragma unroll
      for (int i = 0; i < 2; i++)
#pragma unroll
        for (int j = 0; j < 2; j++)
          acc[i][j] = __builtin_amdgcn_mfma_f32_16x16x32_bf16(afr[i][s], bfr[j], acc[i][j], 0, 0, 0);
    }

    if (more) {
      ushort* d = &Bsh[1 - cur][bdst];
      *(uint4*)d = make_uint4(dec2((uint32_t)nw.x, nS), dec2((uint32_t)nw.y, nS),
                              dec2((uint32_t)nw.z, nS), dec2((uint32_t)nw.w, nS));
#pragma unroll
      for (int i = 0; i < 2; i++)
#pragma unroll
        for (int s = 0; s < 2; s++)
          afr[i][s] = nafr[i][s];
    }
    __syncthreads();
  }

#pragma unroll
  for (int i = 0; i < 2; i++) {
#pragma unroll
    for (int r = 0; r < 4; r++) {
      int mrow = wv*32 + i*16 + q*4 + r;
      int gm = m0 + mrow;
      if (gm < cnt) {
        if (use_ye) {
          ushort* dst = ye + (size_t)(obase + gm)*DDIM + n0 + l16;
#pragma unroll
          for (int j = 0; j < 2; j++) {
            uint32_t bb = __float_as_uint(acc[i][j][r]);
            bb += 0x7FFFu + ((bb >> 16) & 1u);
            dst[j*16] = (ushort)(bb >> 16);
          }
        } else {
          int tok = toks[mrow];
          float* dst = out + (size_t)tok*DDIM + n0 + l16;
#pragma unroll
          for (int j = 0; j < 2; j++) atomicAdd(&dst[j*16], acc[i][j][r]);
        }
      }
    }
  }
}

// ---------- combine: out[t,:] = sum of routed ye rows (bf16 -> fp32) ----------
__global__ void combine_kernel(const ushort* __restrict__ ye, const int* __restrict__ offsets,
                               const int* __restrict__ tpe, const int* __restrict__ tps,
                               const int* __restrict__ tpn, float* __restrict__ out) {
  int t = blockIdx.x;
  int np = tpn[t];
  int rows[TOPK];
#pragma unroll
  for (int j = 0; j < TOPK; j++)
    rows[j] = (j < np) ? (offsets[tpe[t*TOPK+j]] + tps[t*TOPK+j]) : -1;
  for (int c = threadIdx.x; c < DDIM; c += 256) {
    float s = 0.f;
#pragma unroll
    for (int j = 0; j < TOPK; j++)
      if (rows[j] >= 0)
        s += __uint_as_float(((uint32_t)ye[(size_t)rows[j]*DDIM + c]) << 16);
    out[(size_t)t*DDIM + c] = s;
  }
}

extern "C" void kernel_launch(void* const* d_in, const int* in_sizes, int n_in,
                              void* d_out, int out_size, void* d_ws, size_t ws_size,
                              hipStream_t stream)
{
  const float* x    = (const float*)d_in[0];
  const float* tw   = (const float*)d_in[1];
  const int*   tids = (const int*)d_in[2];
  const int*   w13  = (const int*)d_in[3];
  const int*   w13s = (const int*)d_in[4];
  const int*   w2   = (const int*)d_in[5];
  const int*   w2s  = (const int*)d_in[6];
  float* out = (float*)d_out;

  char* ws = (char*)d_ws;
  size_t off = 0;
  auto alloc = [&](size_t bytes) { void* p = ws + off; off = (off + bytes + 255) & ~(size_t)255; return p; };
  ushort* xq     = (ushort*)alloc((size_t)T_TOK*DDIM*2);        // 2 MB
  int*   counts  = (int*)alloc(64*4);
  int*   offsets = (int*)alloc(64*4);
  int*   lists   = (int*)alloc((size_t)NEXP*T_TOK*4);
  float* combs   = (float*)alloc((size_t)NEXP*T_TOK*4);
  int*   tpe     = (int*)alloc((size_t)T_TOK*TOPK*4);
  int*   tps     = (int*)alloc((size_t)T_TOK*TOPK*4);
  int*   tpn     = (int*)alloc((size_t)T_TOK*4);
  ushort* a_buf  = (ushort*)alloc((size_t)T_TOK*TOPK*IDIM*2);   // 6 MB
  ushort* ye     = (ushort*)(ws + off);
  size_t need_ye = off + (size_t)T_TOK*TOPK*DDIM*2;             // +16 MB => ~24.3 MB total
  int use_ye = (ws_size >= need_ye) ? 1 : 0;

  hipMemsetAsync(counts, 0, 256, stream);
  hipMemsetAsync(out, 0, (size_t)out_size * 4, stream);

  qdq_kernel<<<(T_TOK*DDIM)/256, 256, 0, stream>>>(x, xq);
  route_kernel<<<1, T_TOK, 0, stream>>>(tids, tw, counts, offsets, lists, combs, tpe, tps, tpn);
  gemm1_kernel<<<dim3(NEXP, IDIM/16, 4), 256, 0, stream>>>(
      xq, w13, w13s, counts, offsets, lists, combs, a_buf);
  gemm2_kernel<<<dim3(NEXP, DDIM/32, 4), 256, 0, stream>>>(
      a_buf, w2, w2s, counts, offsets, lists, out, ye, use_ye);
  if (use_ye)
    combine_kernel<<<T_TOK, 256, 0, stream>>>(ye, offsets, tpe, tps, tpn, out);
}

// Round 7
// 369.792 us; speedup vs baseline: 1.0314x; 1.0314x over previous
//
#include <hip/hip_runtime.h>
#include <stdint.h>
#include <math.h>

#define T_TOK 512
#define DDIM  2048
#define IDIM  768
#define NEXP  16
#define TOPK  8
#define LDB   72   // LDS B row stride (bf16 units)
#define YW    512  // ye slice width (DDIM/4)

typedef __attribute__((ext_vector_type(8))) short bf16x8;
typedef __attribute__((ext_vector_type(4))) float f32x4;

// ---------- fp8 e4m3fn RTNE quant-dequant (fp32-exact, result fits bf16) ----------
__device__ __forceinline__ float e4m3_rtne(float f) {
  uint32_t u = __float_as_uint(f);
  uint32_t sign = u & 0x80000000u;
  uint32_t a = u & 0x7FFFFFFFu;
  float fa = __uint_as_float(a);
  float out;
  if (fa >= 0.015625f) {            // normal: keep 3 mantissa bits, RTNE
    uint32_t lsb = (a >> 20) & 1u;
    a += 0x0007FFFFu + lsb;
    a &= 0xFFF00000u;
    out = __uint_as_float(a);
  } else {                          // subnormal: quantum 2^-9
    out = rintf(fa * 512.0f) * 0.001953125f;
  }
  return __uint_as_float(__float_as_uint(out) | sign);
}

__global__ void qdq_kernel(const float* __restrict__ x, ushort* __restrict__ xq) {
  int idx = blockIdx.x * 256 + threadIdx.x;
  float v = x[idx];
  float a = fabsf(v);
#pragma unroll
  for (int m = 16; m >= 1; m >>= 1)
    a = fmaxf(a, __shfl_xor(a, m, 32));
  a = fmaxf(a, 1e-4f);
  float scale = a / 448.0f;
  uint32_t b = __float_as_uint(scale);
  uint32_t ex = ((b >> 23) & 255u) + ((b & 0x7FFFFFu) ? 1u : 0u);
  ex = ex < 1u ? 1u : (ex > 254u ? 254u : ex);
  float rscale = __uint_as_float(ex << 23);
  float inv = 1.0f / rscale;
  float r = e4m3_rtne(v * inv) * rscale;       // exactly representable in bf16
  xq[idx] = (ushort)(__float_as_uint(r) >> 16);
}

// ---------- routing ----------
__global__ void route_kernel(const int* __restrict__ ids, const float* __restrict__ wts,
                             int* counts, int* offsets, short* lists, float* combs,
                             ushort* tpp, int* tpn) {
  int t = threadIdx.x;  // 512 threads
  int  myid[TOPK];
  float myw[TOPK];
#pragma unroll
  for (int k = 0; k < TOPK; k++) { myid[k] = ids[t*TOPK+k]; myw[k] = wts[t*TOPK+k]; }
  int np = 0;
  for (int e = 0; e < NEXP; e++) {
    float s = 0.f; bool r = false;
#pragma unroll
    for (int k = 0; k < TOPK; k++) if (myid[k] == e) { s += myw[k]; r = true; }
    if (r) {
      int slot = atomicAdd(&counts[e], 1);
      lists[(e<<9) + slot] = (short)t;
      combs[(e<<9) + slot] = s;
      tpp[t*TOPK + np] = (ushort)((e << 12) | slot);   // pack expert+slot
      np++;
    }
  }
  tpn[t] = np;
  __syncthreads();
  if (t == 0) {
    int acc = 0;
    for (int e = 0; e < NEXP; e++) {
      offsets[e] = acc;
      acc += atomicAdd(&counts[e], 0);
    }
    offsets[NEXP] = acc;
  }
}

// ---------- fp4 int (1 byte payload) -> packed 2x bf16; S = (sf-1)<<1 ----------
__device__ __forceinline__ uint32_t dec2(uint32_t w8, uint32_t S) {
  uint32_t lo = w8 & 15u, hi = (w8 >> 4) & 15u;
  uint32_t mlo = lo & 7u, mhi = hi & 7u;
  uint32_t clo = (mlo < 2u) ? 0u : mlo;
  uint32_t chi = (mhi < 2u) ? 0u : mhi;
  uint32_t blo = (mlo == 0u) ? 0u : ((S + clo) << 6);
  uint32_t bhi = (mhi == 0u) ? 0u : ((S + chi) << 6);
  blo |= (lo & 8u) << 12;
  bhi |= (hi & 8u) << 12;
  return blo | (bhi << 16);
}

// ---------- GEMM1: M=128 (4 waves x 32 rows), N=32 i-cols (gate+up), BK=64, pipelined ----------
__global__ __launch_bounds__(256,3) void gemm1_kernel(
    const ushort* __restrict__ xq, const int* __restrict__ w13,
    const int* __restrict__ w13s, const int* __restrict__ counts,
    const int* __restrict__ offsets, const short* __restrict__ lists,
    const float* __restrict__ combs, ushort* __restrict__ a_buf)
{
  const int e  = blockIdx.x;
  const int i0 = blockIdx.y << 5;
  const int m0 = blockIdx.z << 7;
  const int cnt = counts[e];
  if (m0 >= cnt) return;

  __shared__ __align__(16) ushort Bsh[2][64*LDB];   // 2 x 9 KB double buffer
  __shared__ int   toks[128];
  __shared__ float cmbs[128];

  const int tid = threadIdx.x;
  if (tid < 128) {
    int m = m0 + tid; bool v = m < cnt;
    toks[tid] = v ? (int)lists[(e<<9)+m] : 0;
    cmbs[tid] = v ? combs[(e<<9)+m] : 0.f;
  }
  __syncthreads();

  const int wv = tid >> 6, l = tid & 63, l16 = l & 15, q = l >> 4;

  // A sources: wave wv covers rows wv*32 + i*16 + l16, i<2
  const ushort* arow[2];
#pragma unroll
  for (int i = 0; i < 2; i++)
    arow[i] = xq + (size_t)toks[wv*32 + i*16 + l16]*DDIM + q*8;

  // B staging: 64 rows (32 gate + 32 up) x 64 k per iter; 4 threads/row, 8 ints each
  const int rb = tid >> 2, hq = tid & 3;
  const int feat = (rb < 32) ? (i0 + rb) : (IDIM + i0 + (rb - 32));
  const int* wrow = w13 + ((size_t)e*(2*IDIM) + feat)*(DDIM/2) + hq*8;
  const int* srow = w13s + ((size_t)e*(2*IDIM) + feat)*(DDIM/32) + (hq >> 1);
  const int bdst = rb*LDB + hq*16;

  f32x4 acc[2][4];
#pragma unroll
  for (int i = 0; i < 2; i++)
#pragma unroll
    for (int j = 0; j < 4; j++) acc[i][j] = (f32x4){0.f,0.f,0.f,0.f};

  // ---- prologue: load + dequant iter 0 ----
  bf16x8 afr[2][2];
#pragma unroll
  for (int i = 0; i < 2; i++)
#pragma unroll
    for (int s = 0; s < 2; s++)
      afr[i][s] = *(const bf16x8*)(arow[i] + s*32);
  {
    int4 w0 = *(const int4*)(wrow);
    int4 w1 = *(const int4*)(wrow + 4);
    uint32_t S = (((uint32_t)srow[0]) - 1u) << 1;
    int wi[8] = {w0.x,w0.y,w0.z,w0.w, w1.x,w1.y,w1.z,w1.w};
    uint32_t od[8];
#pragma unroll
    for (int c = 0; c < 8; c++) od[c] = dec2((uint32_t)wi[c], S);
    ushort* d = &Bsh[0][bdst];
    *(uint4*)d       = make_uint4(od[0], od[1], od[2], od[3]);
    *(uint4*)(d + 8) = make_uint4(od[4], od[5], od[6], od[7]);
  }
  __syncthreads();

  for (int k0 = 0; k0 < DDIM; k0 += 64) {
    const int cur = (k0 >> 6) & 1;
    const bool more = (k0 + 64) < DDIM;

    // issue next iter's global loads
    int4 nw0, nw1; uint32_t nS = 0;
    bf16x8 nafr[2][2];
    if (more) {
      const int* wp = wrow + ((k0 + 64) >> 1);
      nw0 = *(const int4*)wp;
      nw1 = *(const int4*)(wp + 4);
      nS = (((uint32_t)srow[(k0 + 64) >> 5]) - 1u) << 1;
#pragma unroll
      for (int i = 0; i < 2; i++)
#pragma unroll
        for (int s = 0; s < 2; s++)
          nafr[i][s] = *(const bf16x8*)(arow[i] + k0 + 64 + s*32);
    }

    // compute current iter
#pragma unroll
    for (int s = 0; s < 2; s++) {
      bf16x8 bfr[4];
#pragma unroll
      for (int j = 0; j < 4; j++)
        bfr[j] = *(const bf16x8*)&Bsh[cur][(j*16 + l16)*LDB + s*32 + q*8];
#pragma unroll
      for (int i = 0; i < 2; i++)
#pragma unroll
        for (int j = 0; j < 4; j++)
          acc[i][j] = __builtin_amdgcn_mfma_f32_16x16x32_bf16(afr[i][s], bfr[j], acc[i][j], 0, 0, 0);
    }

    // dequant next into the other buffer
    if (more) {
      int wi[8] = {nw0.x,nw0.y,nw0.z,nw0.w, nw1.x,nw1.y,nw1.z,nw1.w};
      uint32_t od[8];
#pragma unroll
      for (int c = 0; c < 8; c++) od[c] = dec2((uint32_t)wi[c], nS);
      ushort* d = &Bsh[1 - cur][bdst];
      *(uint4*)d       = make_uint4(od[0], od[1], od[2], od[3]);
      *(uint4*)(d + 8) = make_uint4(od[4], od[5], od[6], od[7]);
#pragma unroll
      for (int i = 0; i < 2; i++)
#pragma unroll
        for (int s = 0; s < 2; s++)
          afr[i][s] = nafr[i][s];
    }
    __syncthreads();
  }

  const int obase = offsets[e];
#pragma unroll
  for (int i = 0; i < 2; i++) {
#pragma unroll
    for (int r = 0; r < 4; r++) {
      int mrow = wv*32 + i*16 + q*4 + r;   // C/D: row=(lane>>4)*4+reg, col=lane&15
      int gm = m0 + mrow;
      if (gm < cnt) {
        float c = cmbs[mrow];
        ushort* dst = a_buf + (size_t)(obase + gm)*IDIM + i0 + l16;
#pragma unroll
        for (int jj = 0; jj < 2; jj++) {
          float g = acc[i][jj][r], u = acc[i][jj+2][r];
          float val = (g / (1.f + expf(-g))) * u * c;   // comb folded (linear downstream)
          uint32_t bb = __float_as_uint(val);
          bb += 0x7FFFu + ((bb >> 16) & 1u);            // RTNE to bf16
          dst[jj*16] = (ushort)(bb >> 16);
        }
      }
    }
  }
}

// ---------- GEMM2: M=128 (4 waves x 32), N=64 d-cols, BK=64, pipelined; D-slice yb ----------
__global__ __launch_bounds__(256,3) void gemm2_kernel(
    const ushort* __restrict__ a_buf, const int* __restrict__ w2,
    const int* __restrict__ w2s, const int* __restrict__ counts,
    const int* __restrict__ offsets, const short* __restrict__ lists,
    float* __restrict__ out, ushort* __restrict__ ye, int use_ye, int yb)
{
  const int e  = blockIdx.x;
  const int n0 = yb + (blockIdx.y << 6);    // global d-col of this 64-wide tile
  const int m0 = blockIdx.z << 7;
  const int cnt = counts[e];
  if (m0 >= cnt) return;

  __shared__ __align__(16) ushort Bsh[2][64*LDB];
  __shared__ int toks[128];

  const int tid = threadIdx.x;
  if (tid < 128) {
    int m = m0 + tid;
    toks[tid] = (m < cnt) ? (int)lists[(e<<9)+m] : -1;
  }
  __syncthreads();

  const int wv = tid >> 6, l = tid & 63, l16 = l & 15, q = l >> 4;
  const int obase = offsets[e];

  const ushort* arow[2];
#pragma unroll
  for (int i = 0; i < 2; i++) {
    int gm = m0 + wv*32 + i*16 + l16;
    int rowc = (gm < cnt) ? gm : 0;
    arow[i] = a_buf + (size_t)(obase + rowc)*IDIM + q*8;
  }

  const int rb = tid >> 2, hq = tid & 3;
  const int* wrow = w2 + ((size_t)e*DDIM + n0 + rb)*(IDIM/2) + hq*8;
  const int* srow = w2s + ((size_t)e*DDIM + n0 + rb)*(IDIM/32) + (hq >> 1);
  const int bdst = rb*LDB + hq*16;

  f32x4 acc[2][4];
#pragma unroll
  for (int i = 0; i < 2; i++)
#pragma unroll
    for (int j = 0; j < 4; j++) acc[i][j] = (f32x4){0.f,0.f,0.f,0.f};

  bf16x8 afr[2][2];
#pragma unroll
  for (int i = 0; i < 2; i++)
#pragma unroll
    for (int s = 0; s < 2; s++)
      afr[i][s] = *(const bf16x8*)(arow[i] + s*32);
  {
    int4 w0 = *(const int4*)(wrow);
    int4 w1 = *(const int4*)(wrow + 4);
    uint32_t S = (((uint32_t)srow[0]) - 1u) << 1;
    int wi[8] = {w0.x,w0.y,w0.z,w0.w, w1.x,w1.y,w1.z,w1.w};
    uint32_t od[8];
#pragma unroll
    for (int c = 0; c < 8; c++) od[c] = dec2((uint32_t)wi[c], S);
    ushort* d = &Bsh[0][bdst];
    *(uint4*)d       = make_uint4(od[0], od[1], od[2], od[3]);
    *(uint4*)(d + 8) = make_uint4(od[4], od[5], od[6], od[7]);
  }
  __syncthreads();

  for (int k0 = 0; k0 < IDIM; k0 += 64) {
    const int cur = (k0 >> 6) & 1;
    const bool more = (k0 + 64) < IDIM;

    int4 nw0, nw1; uint32_t nS = 0;
    bf16x8 nafr[2][2];
    if (more) {
      const int* wp = wrow + ((k0 + 64) >> 1);
      nw0 = *(const int4*)wp;
      nw1 = *(const int4*)(wp + 4);
      nS = (((uint32_t)srow[(k0 + 64) >> 5]) - 1u) << 1;
#pragma unroll
      for (int i = 0; i < 2; i++)
#pragma unroll
        for (int s = 0; s < 2; s++)
          nafr[i][s] = *(const bf16x8*)(arow[i] + k0 + 64 + s*32);
    }

#pragma unroll
    for (int s = 0; s < 2; s++) {
      bf16x8 bfr[4];
#pragma unroll
      for (int j = 0; j < 4; j++)
        bfr[j] = *(const bf16x8*)&Bsh[cur][(j*16 + l16)*LDB + s*32 + q*8];
#pragma unroll
      for (int i = 0; i < 2; i++)
#pragma unroll
        for (int j = 0; j < 4; j++)
          acc[i][j] = __builtin_amdgcn_mfma_f32_16x16x32_bf16(afr[i][s], bfr[j], acc[i][j], 0, 0, 0);
    }

    if (more) {
      int wi[8] = {nw0.x,nw0.y,nw0.z,nw0.w, nw1.x,nw1.y,nw1.z,nw1.w};
      uint32_t od[8];
#pragma unroll
      for (int c = 0; c < 8; c++) od[c] = dec2((uint32_t)wi[c], nS);
      ushort* d = &Bsh[1 - cur][bdst];
      *(uint4*)d       = make_uint4(od[0], od[1], od[2], od[3]);
      *(uint4*)(d + 8) = make_uint4(od[4], od[5], od[6], od[7]);
#pragma unroll
      for (int i = 0; i < 2; i++)
#pragma unroll
        for (int s = 0; s < 2; s++)
          afr[i][s] = nafr[i][s];
    }
    __syncthreads();
  }

#pragma unroll
  for (int i = 0; i < 2; i++) {
#pragma unroll
    for (int r = 0; r < 4; r++) {
      int mrow = wv*32 + i*16 + q*4 + r;
      int gm = m0 + mrow;
      if (gm < cnt) {
        if (use_ye) {
          ushort* dst = ye + (size_t)(obase + gm)*YW + (n0 - yb) + l16;
#pragma unroll
          for (int j = 0; j < 4; j++) {
            uint32_t bb = __float_as_uint(acc[i][j][r]);
            bb += 0x7FFFu + ((bb >> 16) & 1u);
            dst[j*16] = (ushort)(bb >> 16);
          }
        } else {
          int tok = toks[mrow];
          float* dst = out + (size_t)tok*DDIM + n0 + l16;
#pragma unroll
          for (int j = 0; j < 4; j++) atomicAdd(&dst[j*16], acc[i][j][r]);
        }
      }
    }
  }
}

// ---------- combine (one D-slice): out[t, yb+c] = sum of routed ye rows ----------
__global__ void combine_kernel(const ushort* __restrict__ ye, const int* __restrict__ offsets,
                               const ushort* __restrict__ tpp, const int* __restrict__ tpn,
                               float* __restrict__ out, int yb) {
  int t = blockIdx.x;
  int np = tpn[t];
  int rows[TOPK];
#pragma unroll
  for (int j = 0; j < TOPK; j++) {
    if (j < np) {
      uint32_t v = tpp[t*TOPK + j];
      rows[j] = offsets[v >> 12] + (int)(v & 0xFFFu);
    } else rows[j] = -1;
  }
  for (int c = threadIdx.x; c < YW; c += 256) {
    float s = 0.f;
#pragma unroll
    for (int j = 0; j < TOPK; j++)
      if (rows[j] >= 0)
        s += __uint_as_float(((uint32_t)ye[(size_t)rows[j]*YW + c]) << 16);
    out[(size_t)t*DDIM + yb + c] = s;
  }
}

extern "C" void kernel_launch(void* const* d_in, const int* in_sizes, int n_in,
                              void* d_out, int out_size, void* d_ws, size_t ws_size,
                              hipStream_t stream)
{
  const float* x    = (const float*)d_in[0];
  const float* tw   = (const float*)d_in[1];
  const int*   tids = (const int*)d_in[2];
  const int*   w13  = (const int*)d_in[3];
  const int*   w13s = (const int*)d_in[4];
  const int*   w2   = (const int*)d_in[5];
  const int*   w2s  = (const int*)d_in[6];
  float* out = (float*)d_out;

  char* ws = (char*)d_ws;
  size_t off = 0;
  auto alloc = [&](size_t bytes) { void* p = ws + off; off = (off + bytes + 255) & ~(size_t)255; return p; };
  ushort* a_buf  = (ushort*)alloc((size_t)T_TOK*TOPK*IDIM*2);   // 6.29 MB
  ushort* ye     = (ushort*)alloc((size_t)T_TOK*TOPK*YW*2);     // 4.19 MB (one D-slice)
  ushort* xq     = (ushort*)alloc((size_t)T_TOK*DDIM*2);        // 2.10 MB
  float* combs   = (float*)alloc((size_t)NEXP*T_TOK*4);
  short* lists   = (short*)alloc((size_t)NEXP*T_TOK*2);
  ushort* tpp    = (ushort*)alloc((size_t)T_TOK*TOPK*2);
  int*   tpn     = (int*)alloc((size_t)T_TOK*4);
  int*   counts  = (int*)alloc(64*4);
  int*   offsets = (int*)alloc(64*4);
  size_t need = off;                                            // ~12.7 MB total
  int use_ye = (ws_size >= need) ? 1 : 0;

  hipMemsetAsync(counts, 0, 256, stream);
  hipMemsetAsync(out, 0, (size_t)out_size * 4, stream);

  qdq_kernel<<<(T_TOK*DDIM)/256, 256, 0, stream>>>(x, xq);
  route_kernel<<<1, T_TOK, 0, stream>>>(tids, tw, counts, offsets, lists, combs, tpp, tpn);
  gemm1_kernel<<<dim3(NEXP, IDIM/32, 4), 256, 0, stream>>>(
      xq, w13, w13s, counts, offsets, lists, combs, a_buf);
  for (int p = 0; p < DDIM/YW; p++) {
    gemm2_kernel<<<dim3(NEXP, YW/64, 4), 256, 0, stream>>>(
        a_buf, w2, w2s, counts, offsets, lists, out, ye, use_ye, p*YW);
    if (use_ye)
      combine_kernel<<<T_TOK, 256, 0, stream>>>(ye, offsets, tpp, tpn, out, p*YW);
  }
}

// Round 8
// 310.309 us; speedup vs baseline: 1.2291x; 1.1917x over previous
//
#include <hip/hip_runtime.h>
#include <stdint.h>
#include <math.h>

#define T_TOK 512
#define DDIM  2048
#define IDIM  768
#define NEXP  16
#define TOPK  8
#define LDB   72    // LDS B row stride (bf16 units)
#define YW    1024  // ye slice width (DDIM/2)

typedef __attribute__((ext_vector_type(8))) short bf16x8;
typedef __attribute__((ext_vector_type(4))) float f32x4;

// ---------- fp8 e4m3fn RTNE quant-dequant (fp32-exact, result fits bf16) ----------
__device__ __forceinline__ float e4m3_rtne(float f) {
  uint32_t u = __float_as_uint(f);
  uint32_t sign = u & 0x80000000u;
  uint32_t a = u & 0x7FFFFFFFu;
  float fa = __uint_as_float(a);
  float out;
  if (fa >= 0.015625f) {            // normal: keep 3 mantissa bits, RTNE
    uint32_t lsb = (a >> 20) & 1u;
    a += 0x0007FFFFu + lsb;
    a &= 0xFFF00000u;
    out = __uint_as_float(a);
  } else {                          // subnormal: quantum 2^-9
    out = rintf(fa * 512.0f) * 0.001953125f;
  }
  return __uint_as_float(__float_as_uint(out) | sign);
}

// ---------- fused qdq (blocks 0..N-2) + routing (last block) ----------
__global__ __launch_bounds__(512) void qdq_route_kernel(
    const float* __restrict__ x, ushort* __restrict__ xq,
    const int* __restrict__ ids, const float* __restrict__ wts,
    int* __restrict__ counts, int* __restrict__ offsets,
    short* __restrict__ lists, float* __restrict__ combs,
    ushort* __restrict__ tpp, int* __restrict__ tpn)
{
  if ((int)blockIdx.x < (int)gridDim.x - 1) {
    // qdq: 4 elems/thread; 8 consecutive lanes = one 32-group
    int idx4 = blockIdx.x * 512 + threadIdx.x;
    float4 v = ((const float4*)x)[idx4];
    float a = fmaxf(fmaxf(fabsf(v.x), fabsf(v.y)), fmaxf(fabsf(v.z), fabsf(v.w)));
#pragma unroll
    for (int m = 4; m >= 1; m >>= 1)
      a = fmaxf(a, __shfl_xor(a, m, 8));
    a = fmaxf(a, 1e-4f);
    float scale = a / 448.0f;
    uint32_t b = __float_as_uint(scale);
    uint32_t ex = ((b >> 23) & 255u) + ((b & 0x7FFFFFu) ? 1u : 0u);
    ex = ex < 1u ? 1u : (ex > 254u ? 254u : ex);
    float rscale = __uint_as_float(ex << 23);
    float inv = 1.0f / rscale;
    uint32_t r0 = __float_as_uint(e4m3_rtne(v.x * inv) * rscale) >> 16;
    uint32_t r1 = __float_as_uint(e4m3_rtne(v.y * inv) * rscale) >> 16;
    uint32_t r2 = __float_as_uint(e4m3_rtne(v.z * inv) * rscale) >> 16;
    uint32_t r3 = __float_as_uint(e4m3_rtne(v.w * inv) * rscale) >> 16;
    ((uint2*)xq)[idx4] = make_uint2(r0 | (r1 << 16), r2 | (r3 << 16));
  } else {
    // routing: 512 threads, LDS counters
    __shared__ int scnt[NEXP];
    int t = threadIdx.x;
    if (t < NEXP) scnt[t] = 0;
    __syncthreads();
    int  myid[TOPK];
    float myw[TOPK];
#pragma unroll
    for (int k = 0; k < TOPK; k++) { myid[k] = ids[t*TOPK+k]; myw[k] = wts[t*TOPK+k]; }
    int np = 0;
    for (int e = 0; e < NEXP; e++) {
      float s = 0.f; bool r = false;
#pragma unroll
      for (int k = 0; k < TOPK; k++) if (myid[k] == e) { s += myw[k]; r = true; }
      if (r) {
        int slot = atomicAdd(&scnt[e], 1);
        lists[(e<<9) + slot] = (short)t;
        combs[(e<<9) + slot] = s;
        tpp[t*TOPK + np] = (ushort)((e << 12) | slot);
        np++;
      }
    }
    tpn[t] = np;
    __syncthreads();
    if (t == 0) {
      int acc = 0;
      for (int e = 0; e < NEXP; e++) {
        offsets[e] = acc;
        int c = scnt[e];
        counts[e] = c;
        acc += c;
      }
      offsets[NEXP] = acc;
    }
  }
}

// ---------- fp4 int (1 byte payload) -> packed 2x bf16; S = (sf-1)<<1 ----------
__device__ __forceinline__ uint32_t dec2(uint32_t w8, uint32_t S) {
  uint32_t lo = w8 & 15u, hi = (w8 >> 4) & 15u;
  uint32_t mlo = lo & 7u, mhi = hi & 7u;
  uint32_t clo = (mlo < 2u) ? 0u : mlo;
  uint32_t chi = (mhi < 2u) ? 0u : mhi;
  uint32_t blo = (mlo == 0u) ? 0u : ((S + clo) << 6);
  uint32_t bhi = (mhi == 0u) ? 0u : ((S + chi) << 6);
  blo |= (lo & 8u) << 12;
  bhi |= (hi & 8u) << 12;
  return blo | (bhi << 16);
}

// ---------- GEMM1: M=128 (4 waves x 32 rows), N=32 i-cols (gate+up), BK=64, pipelined ----------
__global__ __launch_bounds__(256,3) void gemm1_kernel(
    const ushort* __restrict__ xq, const int* __restrict__ w13,
    const int* __restrict__ w13s, const int* __restrict__ counts,
    const int* __restrict__ offsets, const short* __restrict__ lists,
    const float* __restrict__ combs, ushort* __restrict__ a_buf)
{
  const int e  = blockIdx.x;
  const int i0 = blockIdx.y << 5;
  const int m0 = blockIdx.z << 7;
  const int cnt = counts[e];
  if (m0 >= cnt) return;

  __shared__ __align__(16) ushort Bsh[2][64*LDB];   // 2 x 9 KB double buffer
  __shared__ int   toks[128];
  __shared__ float cmbs[128];

  const int tid = threadIdx.x;
  if (tid < 128) {
    int m = m0 + tid; bool v = m < cnt;
    toks[tid] = v ? (int)lists[(e<<9)+m] : 0;
    cmbs[tid] = v ? combs[(e<<9)+m] : 0.f;
  }
  __syncthreads();

  const int wv = tid >> 6, l = tid & 63, l16 = l & 15, q = l >> 4;

  const ushort* arow[2];
#pragma unroll
  for (int i = 0; i < 2; i++)
    arow[i] = xq + (size_t)toks[wv*32 + i*16 + l16]*DDIM + q*8;

  const int rb = tid >> 2, hq = tid & 3;
  const int feat = (rb < 32) ? (i0 + rb) : (IDIM + i0 + (rb - 32));
  const int* wrow = w13 + ((size_t)e*(2*IDIM) + feat)*(DDIM/2) + hq*8;
  const int* srow = w13s + ((size_t)e*(2*IDIM) + feat)*(DDIM/32) + (hq >> 1);
  const int bdst = rb*LDB + hq*16;

  f32x4 acc[2][4];
#pragma unroll
  for (int i = 0; i < 2; i++)
#pragma unroll
    for (int j = 0; j < 4; j++) acc[i][j] = (f32x4){0.f,0.f,0.f,0.f};

  bf16x8 afr[2][2];
#pragma unroll
  for (int i = 0; i < 2; i++)
#pragma unroll
    for (int s = 0; s < 2; s++)
      afr[i][s] = *(const bf16x8*)(arow[i] + s*32);
  {
    int4 w0 = *(const int4*)(wrow);
    int4 w1 = *(const int4*)(wrow + 4);
    uint32_t S = (((uint32_t)srow[0]) - 1u) << 1;
    int wi[8] = {w0.x,w0.y,w0.z,w0.w, w1.x,w1.y,w1.z,w1.w};
    uint32_t od[8];
#pragma unroll
    for (int c = 0; c < 8; c++) od[c] = dec2((uint32_t)wi[c], S);
    ushort* d = &Bsh[0][bdst];
    *(uint4*)d       = make_uint4(od[0], od[1], od[2], od[3]);
    *(uint4*)(d + 8) = make_uint4(od[4], od[5], od[6], od[7]);
  }
  __syncthreads();

  for (int k0 = 0; k0 < DDIM; k0 += 64) {
    const int cur = (k0 >> 6) & 1;
    const bool more = (k0 + 64) < DDIM;

    int4 nw0, nw1; uint32_t nS = 0;
    bf16x8 nafr[2][2];
    if (more) {
      const int* wp = wrow + ((k0 + 64) >> 1);
      nw0 = *(const int4*)wp;
      nw1 = *(const int4*)(wp + 4);
      nS = (((uint32_t)srow[(k0 + 64) >> 5]) - 1u) << 1;
#pragma unroll
      for (int i = 0; i < 2; i++)
#pragma unroll
        for (int s = 0; s < 2; s++)
          nafr[i][s] = *(const bf16x8*)(arow[i] + k0 + 64 + s*32);
    }

#pragma unroll
    for (int s = 0; s < 2; s++) {
      bf16x8 bfr[4];
#pragma unroll
      for (int j = 0; j < 4; j++)
        bfr[j] = *(const bf16x8*)&Bsh[cur][(j*16 + l16)*LDB + s*32 + q*8];
#pragma unroll
      for (int i = 0; i < 2; i++)
#pragma unroll
        for (int j = 0; j < 4; j++)
          acc[i][j] = __builtin_amdgcn_mfma_f32_16x16x32_bf16(afr[i][s], bfr[j], acc[i][j], 0, 0, 0);
    }

    if (more) {
      int wi[8] = {nw0.x,nw0.y,nw0.z,nw0.w, nw1.x,nw1.y,nw1.z,nw1.w};
      uint32_t od[8];
#pragma unroll
      for (int c = 0; c < 8; c++) od[c] = dec2((uint32_t)wi[c], nS);
      ushort* d = &Bsh[1 - cur][bdst];
      *(uint4*)d       = make_uint4(od[0], od[1], od[2], od[3]);
      *(uint4*)(d + 8) = make_uint4(od[4], od[5], od[6], od[7]);
#pragma unroll
      for (int i = 0; i < 2; i++)
#pragma unroll
        for (int s = 0; s < 2; s++)
          afr[i][s] = nafr[i][s];
    }
    __syncthreads();
  }

  const int obase = offsets[e];
#pragma unroll
  for (int i = 0; i < 2; i++) {
#pragma unroll
    for (int r = 0; r < 4; r++) {
      int mrow = wv*32 + i*16 + q*4 + r;   // C/D: row=(lane>>4)*4+reg, col=lane&15
      int gm = m0 + mrow;
      if (gm < cnt) {
        float c = cmbs[mrow];
        ushort* dst = a_buf + (size_t)(obase + gm)*IDIM + i0 + l16;
#pragma unroll
        for (int jj = 0; jj < 2; jj++) {
          float g = acc[i][jj][r], u = acc[i][jj+2][r];
          float val = (g / (1.f + expf(-g))) * u * c;   // comb folded (linear downstream)
          uint32_t bb = __float_as_uint(val);
          bb += 0x7FFFu + ((bb >> 16) & 1u);            // RTNE to bf16
          dst[jj*16] = (ushort)(bb >> 16);
        }
      }
    }
  }
}

// ---------- GEMM2: M=128 (4 waves x 32), N=64 d-cols, BK=64, pipelined; ye slice ----------
__global__ __launch_bounds__(256,3) void gemm2_kernel(
    const ushort* __restrict__ a_buf, const int* __restrict__ w2,
    const int* __restrict__ w2s, const int* __restrict__ counts,
    const int* __restrict__ offsets, ushort* __restrict__ ye, int yb)
{
  const int e  = blockIdx.x;
  const int n0 = yb + (blockIdx.y << 6);    // global d-col of this 64-wide tile
  const int m0 = blockIdx.z << 7;
  const int cnt = counts[e];
  if (m0 >= cnt) return;

  __shared__ __align__(16) ushort Bsh[2][64*LDB];

  const int tid = threadIdx.x;
  const int wv = tid >> 6, l = tid & 63, l16 = l & 15, q = l >> 4;
  const int obase = offsets[e];

  const ushort* arow[2];
#pragma unroll
  for (int i = 0; i < 2; i++) {
    int gm = m0 + wv*32 + i*16 + l16;
    int rowc = (gm < cnt) ? gm : 0;
    arow[i] = a_buf + (size_t)(obase + rowc)*IDIM + q*8;
  }

  const int rb = tid >> 2, hq = tid & 3;
  const int* wrow = w2 + ((size_t)e*DDIM + n0 + rb)*(IDIM/2) + hq*8;
  const int* srow = w2s + ((size_t)e*DDIM + n0 + rb)*(IDIM/32) + (hq >> 1);
  const int bdst = rb*LDB + hq*16;

  f32x4 acc[2][4];
#pragma unroll
  for (int i = 0; i < 2; i++)
#pragma unroll
    for (int j = 0; j < 4; j++) acc[i][j] = (f32x4){0.f,0.f,0.f,0.f};

  bf16x8 afr[2][2];
#pragma unroll
  for (int i = 0; i < 2; i++)
#pragma unroll
    for (int s = 0; s < 2; s++)
      afr[i][s] = *(const bf16x8*)(arow[i] + s*32);
  {
    int4 w0 = *(const int4*)(wrow);
    int4 w1 = *(const int4*)(wrow + 4);
    uint32_t S = (((uint32_t)srow[0]) - 1u) << 1;
    int wi[8] = {w0.x,w0.y,w0.z,w0.w, w1.x,w1.y,w1.z,w1.w};
    uint32_t od[8];
#pragma unroll
    for (int c = 0; c < 8; c++) od[c] = dec2((uint32_t)wi[c], S);
    ushort* d = &Bsh[0][bdst];
    *(uint4*)d       = make_uint4(od[0], od[1], od[2], od[3]);
    *(uint4*)(d + 8) = make_uint4(od[4], od[5], od[6], od[7]);
  }
  __syncthreads();

  for (int k0 = 0; k0 < IDIM; k0 += 64) {
    const int cur = (k0 >> 6) & 1;
    const bool more = (k0 + 64) < IDIM;

    int4 nw0, nw1; uint32_t nS = 0;
    bf16x8 nafr[2][2];
    if (more) {
      const int* wp = wrow + ((k0 + 64) >> 1);
      nw0 = *(const int4*)wp;
      nw1 = *(const int4*)(wp + 4);
      nS = (((uint32_t)srow[(k0 + 64) >> 5]) - 1u) << 1;
#pragma unroll
      for (int i = 0; i < 2; i++)
#pragma unroll
        for (int s = 0; s < 2; s++)
          nafr[i][s] = *(const bf16x8*)(arow[i] + k0 + 64 + s*32);
    }

#pragma unroll
    for (int s = 0; s < 2; s++) {
      bf16x8 bfr[4];
#pragma unroll
      for (int j = 0; j < 4; j++)
        bfr[j] = *(const bf16x8*)&Bsh[cur][(j*16 + l16)*LDB + s*32 + q*8];
#pragma unroll
      for (int i = 0; i < 2; i++)
#pragma unroll
        for (int j = 0; j < 4; j++)
          acc[i][j] = __builtin_amdgcn_mfma_f32_16x16x32_bf16(afr[i][s], bfr[j], acc[i][j], 0, 0, 0);
    }

    if (more) {
      int wi[8] = {nw0.x,nw0.y,nw0.z,nw0.w, nw1.x,nw1.y,nw1.z,nw1.w};
      uint32_t od[8];
#pragma unroll
      for (int c = 0; c < 8; c++) od[c] = dec2((uint32_t)wi[c], nS);
      ushort* d = &Bsh[1 - cur][bdst];
      *(uint4*)d       = make_uint4(od[0], od[1], od[2], od[3]);
      *(uint4*)(d + 8) = make_uint4(od[4], od[5], od[6], od[7]);
#pragma unroll
      for (int i = 0; i < 2; i++)
#pragma unroll
        for (int s = 0; s < 2; s++)
          afr[i][s] = nafr[i][s];
    }
    __syncthreads();
  }

#pragma unroll
  for (int i = 0; i < 2; i++) {
#pragma unroll
    for (int r = 0; r < 4; r++) {
      int mrow = wv*32 + i*16 + q*4 + r;
      int gm = m0 + mrow;
      if (gm < cnt) {
        ushort* dst = ye + (size_t)(obase + gm)*YW + (n0 - yb) + l16;
#pragma unroll
        for (int j = 0; j < 4; j++) {
          uint32_t bb = __float_as_uint(acc[i][j][r]);
          bb += 0x7FFFu + ((bb >> 16) & 1u);
          dst[j*16] = (ushort)(bb >> 16);
        }
      }
    }
  }
}

// ---------- combine (one D-slice): out[t, yb+c] = sum of routed ye rows ----------
__global__ void combine_kernel(const ushort* __restrict__ ye, const int* __restrict__ offsets,
                               const ushort* __restrict__ tpp, const int* __restrict__ tpn,
                               float* __restrict__ out, int yb) {
  int t = blockIdx.x;
  int np = tpn[t];
  int rows[TOPK];
#pragma unroll
  for (int j = 0; j < TOPK; j++) {
    if (j < np) {
      uint32_t v = tpp[t*TOPK + j];
      rows[j] = offsets[v >> 12] + (int)(v & 0xFFFu);
    } else rows[j] = -1;
  }
  for (int c = threadIdx.x; c < YW; c += 256) {
    float s = 0.f;
#pragma unroll
    for (int j = 0; j < TOPK; j++)
      if (rows[j] >= 0)
        s += __uint_as_float(((uint32_t)ye[(size_t)rows[j]*YW + c]) << 16);
    out[(size_t)t*DDIM + yb + c] = s;
  }
}

extern "C" void kernel_launch(void* const* d_in, const int* in_sizes, int n_in,
                              void* d_out, int out_size, void* d_ws, size_t ws_size,
                              hipStream_t stream)
{
  const float* x    = (const float*)d_in[0];
  const float* tw   = (const float*)d_in[1];
  const int*   tids = (const int*)d_in[2];
  const int*   w13  = (const int*)d_in[3];
  const int*   w13s = (const int*)d_in[4];
  const int*   w2   = (const int*)d_in[5];
  const int*   w2s  = (const int*)d_in[6];
  float* out = (float*)d_out;

  char* ws = (char*)d_ws;
  size_t off = 0;
  auto alloc = [&](size_t bytes) { void* p = ws + off; off = (off + bytes + 255) & ~(size_t)255; return p; };
  float* combs   = (float*)alloc((size_t)NEXP*T_TOK*4);
  short* lists   = (short*)alloc((size_t)NEXP*T_TOK*2);
  ushort* tpp    = (ushort*)alloc((size_t)T_TOK*TOPK*2);
  int*   tpn     = (int*)alloc((size_t)T_TOK*4);
  int*   counts  = (int*)alloc(64*4);
  int*   offsets = (int*)alloc(64*4);
  ushort* a_buf  = (ushort*)alloc((size_t)T_TOK*TOPK*IDIM*2);   // 6.29 MB
  ushort* ye     = (ushort*)alloc((size_t)T_TOK*TOPK*YW*2);     // 8.39 MB (one D-slice)
  ushort* xq     = ye;   // alias: xq (2.1 MB) lives in ye's region; dead before gemm2 writes ye
  // total ws use ~14.8 MB (< proven-safe 16.7 MB from R1)

  qdq_route_kernel<<<(T_TOK*DDIM)/2048 + 1, 512, 0, stream>>>(
      x, xq, tids, tw, counts, offsets, lists, combs, tpp, tpn);
  gemm1_kernel<<<dim3(NEXP, IDIM/32, 4), 256, 0, stream>>>(
      xq, w13, w13s, counts, offsets, lists, combs, a_buf);
  for (int p = 0; p < DDIM/YW; p++) {
    gemm2_kernel<<<dim3(NEXP, YW/64, 4), 256, 0, stream>>>(
        a_buf, w2, w2s, counts, offsets, ye, p*YW);
    combine_kernel<<<T_TOK, 256, 0, stream>>>(ye, offsets, tpp, tpn, out, p*YW);
  }
}

// Round 9
// 303.608 us; speedup vs baseline: 1.2562x; 1.0221x over previous
//
#include <hip/hip_runtime.h>
#include <stdint.h>
#include <math.h>

#define T_TOK 512
#define DDIM  2048
#define IDIM  768
#define NEXP  16
#define TOPK  8
#define LDB   72    // LDS B row stride (bf16 units)

typedef __attribute__((ext_vector_type(8))) short bf16x8;
typedef __attribute__((ext_vector_type(4))) float f32x4;

// ---------- fp8 e4m3fn RTNE quant-dequant (fp32-exact, result fits bf16) ----------
__device__ __forceinline__ float e4m3_rtne(float f) {
  uint32_t u = __float_as_uint(f);
  uint32_t sign = u & 0x80000000u;
  uint32_t a = u & 0x7FFFFFFFu;
  float fa = __uint_as_float(a);
  float out;
  if (fa >= 0.015625f) {            // normal: keep 3 mantissa bits, RTNE
    uint32_t lsb = (a >> 20) & 1u;
    a += 0x0007FFFFu + lsb;
    a &= 0xFFF00000u;
    out = __uint_as_float(a);
  } else {                          // subnormal: quantum 2^-9
    out = rintf(fa * 512.0f) * 0.001953125f;
  }
  return __uint_as_float(__float_as_uint(out) | sign);
}

// ---------- fused qdq (blocks 0..N-2) + routing (last block) ----------
__global__ __launch_bounds__(512) void qdq_route_kernel(
    const float* __restrict__ x, ushort* __restrict__ xq,
    const int* __restrict__ ids, const float* __restrict__ wts,
    int* __restrict__ counts, int* __restrict__ offsets,
    short* __restrict__ lists, float* __restrict__ combs,
    ushort* __restrict__ tpp, int* __restrict__ tpn)
{
  if ((int)blockIdx.x < (int)gridDim.x - 1) {
    int idx4 = blockIdx.x * 512 + threadIdx.x;
    float4 v = ((const float4*)x)[idx4];
    float a = fmaxf(fmaxf(fabsf(v.x), fabsf(v.y)), fmaxf(fabsf(v.z), fabsf(v.w)));
#pragma unroll
    for (int m = 4; m >= 1; m >>= 1)
      a = fmaxf(a, __shfl_xor(a, m, 8));
    a = fmaxf(a, 1e-4f);
    float scale = a / 448.0f;
    uint32_t b = __float_as_uint(scale);
    uint32_t ex = ((b >> 23) & 255u) + ((b & 0x7FFFFFu) ? 1u : 0u);
    ex = ex < 1u ? 1u : (ex > 254u ? 254u : ex);
    float rscale = __uint_as_float(ex << 23);
    float inv = 1.0f / rscale;
    uint32_t r0 = __float_as_uint(e4m3_rtne(v.x * inv) * rscale) >> 16;
    uint32_t r1 = __float_as_uint(e4m3_rtne(v.y * inv) * rscale) >> 16;
    uint32_t r2 = __float_as_uint(e4m3_rtne(v.z * inv) * rscale) >> 16;
    uint32_t r3 = __float_as_uint(e4m3_rtne(v.w * inv) * rscale) >> 16;
    ((uint2*)xq)[idx4] = make_uint2(r0 | (r1 << 16), r2 | (r3 << 16));
  } else {
    __shared__ int scnt[NEXP];
    int t = threadIdx.x;
    if (t < NEXP) scnt[t] = 0;
    __syncthreads();
    int  myid[TOPK];
    float myw[TOPK];
#pragma unroll
    for (int k = 0; k < TOPK; k++) { myid[k] = ids[t*TOPK+k]; myw[k] = wts[t*TOPK+k]; }
    int np = 0;
    for (int e = 0; e < NEXP; e++) {
      float s = 0.f; bool r = false;
#pragma unroll
      for (int k = 0; k < TOPK; k++) if (myid[k] == e) { s += myw[k]; r = true; }
      if (r) {
        int slot = atomicAdd(&scnt[e], 1);
        lists[(e<<9) + slot] = (short)t;
        combs[(e<<9) + slot] = s;
        tpp[t*TOPK + np] = (ushort)((e << 12) | slot);
        np++;
      }
    }
    tpn[t] = np;
    __syncthreads();
    if (t == 0) {
      int acc = 0;
      for (int e = 0; e < NEXP; e++) {
        offsets[e] = acc;
        int c = scnt[e];
        counts[e] = c;
        acc += c;
      }
      offsets[NEXP] = acc;
    }
  }
}

// ---------- fp4 int (1 byte payload) -> packed 2x bf16; S = (sf-1)<<1 ----------
__device__ __forceinline__ uint32_t dec2(uint32_t w8, uint32_t S) {
  uint32_t lo = w8 & 15u, hi = (w8 >> 4) & 15u;
  uint32_t mlo = lo & 7u, mhi = hi & 7u;
  uint32_t clo = (mlo < 2u) ? 0u : mlo;
  uint32_t chi = (mhi < 2u) ? 0u : mhi;
  uint32_t blo = (mlo == 0u) ? 0u : ((S + clo) << 6);
  uint32_t bhi = (mhi == 0u) ? 0u : ((S + chi) << 6);
  blo |= (lo & 8u) << 12;
  bhi |= (hi & 8u) << 12;
  return blo | (bhi << 16);
}

__device__ __forceinline__ void deq8(int4 w0, int4 w1, uint32_t S, ushort* dst) {
  int wi[8] = {w0.x,w0.y,w0.z,w0.w, w1.x,w1.y,w1.z,w1.w};
  uint32_t od[8];
#pragma unroll
  for (int c = 0; c < 8; c++) od[c] = dec2((uint32_t)wi[c], S);
  *(uint4*)dst       = make_uint4(od[0], od[1], od[2], od[3]);
  *(uint4*)(dst + 8) = make_uint4(od[4], od[5], od[6], od[7]);
}

// ---------- GEMM1: M=128 (4 waves x 32 rows), N=32 i-cols (gate+up), BK=64 ----------
// Deep pipeline: weight load at sub-iter u consumed (dequant) at u+2; LDS double buffer.
__global__ __launch_bounds__(256,3) void gemm1_kernel(
    const ushort* __restrict__ xq, const int* __restrict__ w13,
    const int* __restrict__ w13s, const int* __restrict__ counts,
    const int* __restrict__ offsets, const short* __restrict__ lists,
    const float* __restrict__ combs, ushort* __restrict__ a_buf)
{
  const int e  = blockIdx.x;
  const int i0 = blockIdx.y << 5;
  const int m0 = blockIdx.z << 7;
  const int cnt = counts[e];
  if (m0 >= cnt) return;
  const int NIT = DDIM / 64;   // 32, even

  __shared__ __align__(16) ushort Bsh[2][64*LDB];
  __shared__ int   toks[128];
  __shared__ float cmbs[128];

  const int tid = threadIdx.x;
  if (tid < 128) {
    int m = m0 + tid; bool v = m < cnt;
    toks[tid] = v ? (int)lists[(e<<9)+m] : 0;
    cmbs[tid] = v ? combs[(e<<9)+m] : 0.f;
  }
  __syncthreads();

  const int wv = tid >> 6, l = tid & 63, l16 = l & 15, q = l >> 4;

  const ushort* arow[2];
#pragma unroll
  for (int i = 0; i < 2; i++)
    arow[i] = xq + (size_t)toks[wv*32 + i*16 + l16]*DDIM + q*8;

  const int rb = tid >> 2, hq = tid & 3;
  const int feat = (rb < 32) ? (i0 + rb) : (IDIM + i0 + (rb - 32));
  const int* wrow = w13 + ((size_t)e*(2*IDIM) + feat)*(DDIM/2) + hq*8;
  const int* srow = w13s + ((size_t)e*(2*IDIM) + feat)*(DDIM/32) + (hq >> 1);
  const int bdst = rb*LDB + hq*16;

  f32x4 acc[2][4];
#pragma unroll
  for (int i = 0; i < 2; i++)
#pragma unroll
    for (int j = 0; j < 4; j++) acc[i][j] = (f32x4){0.f,0.f,0.f,0.f};

  bf16x8 aA[2][2], aB[2][2];
  int4 wA0, wA1, wB0, wB1; uint32_t SA, SB;

  // ---- prologue ----
  { // dequant w(0) -> LDS0
    int4 t0 = *(const int4*)(wrow);
    int4 t1 = *(const int4*)(wrow + 4);
    uint32_t S = (((uint32_t)srow[0]) - 1u) << 1;
    deq8(t0, t1, S, &Bsh[0][bdst]);
  }
#pragma unroll
  for (int i = 0; i < 2; i++)
#pragma unroll
    for (int s = 0; s < 2; s++)
      aA[i][s] = *(const bf16x8*)(arow[i] + s*32);          // a(0)
  wA0 = *(const int4*)(wrow + 32); wA1 = *(const int4*)(wrow + 36);
  SA  = (((uint32_t)srow[2]) - 1u) << 1;                    // w(1)
#pragma unroll
  for (int i = 0; i < 2; i++)
#pragma unroll
    for (int s = 0; s < 2; s++)
      aB[i][s] = *(const bf16x8*)(arow[i] + 64 + s*32);     // a(1)
  __syncthreads();

  for (int t = 0; t < NIT; t += 2) {
    // ---- even sub-iter: MFMA(LDS0, aA); dequant wA=w(t+1)->LDS1; load w(t+2)->wB, a(t+2)->aA
    int t2 = t + 2 < NIT ? t + 2 : NIT - 1;
    wB0 = *(const int4*)(wrow + t2*32);
    wB1 = *(const int4*)(wrow + t2*32 + 4);
    SB  = (((uint32_t)srow[t2*2]) - 1u) << 1;
#pragma unroll
    for (int s = 0; s < 2; s++) {
      bf16x8 bfr[4];
#pragma unroll
      for (int j = 0; j < 4; j++)
        bfr[j] = *(const bf16x8*)&Bsh[0][(j*16 + l16)*LDB + s*32 + q*8];
#pragma unroll
      for (int i = 0; i < 2; i++)
#pragma unroll
        for (int j = 0; j < 4; j++)
          acc[i][j] = __builtin_amdgcn_mfma_f32_16x16x32_bf16(aA[i][s], bfr[j], acc[i][j], 0, 0, 0);
    }
    deq8(wA0, wA1, SA, &Bsh[1][bdst]);
#pragma unroll
    for (int i = 0; i < 2; i++)
#pragma unroll
      for (int s = 0; s < 2; s++)
        aA[i][s] = *(const bf16x8*)(arow[i] + t2*64 + s*32);
    __syncthreads();

    // ---- odd sub-iter: MFMA(LDS1, aB); dequant wB=w(t+2)->LDS0; load w(t+3)->wA, a(t+3)->aB
    int t3 = t + 3 < NIT ? t + 3 : NIT - 1;
    wA0 = *(const int4*)(wrow + t3*32);
    wA1 = *(const int4*)(wrow + t3*32 + 4);
    SA  = (((uint32_t)srow[t3*2]) - 1u) << 1;
#pragma unroll
    for (int s = 0; s < 2; s++) {
      bf16x8 bfr[4];
#pragma unroll
      for (int j = 0; j < 4; j++)
        bfr[j] = *(const bf16x8*)&Bsh[1][(j*16 + l16)*LDB + s*32 + q*8];
#pragma unroll
      for (int i = 0; i < 2; i++)
#pragma unroll
        for (int j = 0; j < 4; j++)
          acc[i][j] = __builtin_amdgcn_mfma_f32_16x16x32_bf16(aB[i][s], bfr[j], acc[i][j], 0, 0, 0);
    }
    deq8(wB0, wB1, SB, &Bsh[0][bdst]);
#pragma unroll
    for (int i = 0; i < 2; i++)
#pragma unroll
      for (int s = 0; s < 2; s++)
        aB[i][s] = *(const bf16x8*)(arow[i] + t3*64 + s*32);
    __syncthreads();
  }

  const int obase = offsets[e];
#pragma unroll
  for (int i = 0; i < 2; i++) {
#pragma unroll
    for (int r = 0; r < 4; r++) {
      int mrow = wv*32 + i*16 + q*4 + r;   // C/D: row=(lane>>4)*4+reg, col=lane&15
      int gm = m0 + mrow;
      if (gm < cnt) {
        float c = cmbs[mrow];
        ushort* dst = a_buf + (size_t)(obase + gm)*IDIM + i0 + l16;
#pragma unroll
        for (int jj = 0; jj < 2; jj++) {
          float g = acc[i][jj][r], u = acc[i][jj+2][r];
          float val = (g / (1.f + expf(-g))) * u * c;   // comb folded (linear downstream)
          uint32_t bb = __float_as_uint(val);
          bb += 0x7FFFu + ((bb >> 16) & 1u);            // RTNE to bf16
          dst[jj*16] = (ushort)(bb >> 16);
        }
      }
    }
  }
}

// ---------- GEMM2: M=128 (4 waves x 32), N=64 d-cols, BK=64, same pipeline ----------
__global__ __launch_bounds__(256,3) void gemm2_kernel(
    const ushort* __restrict__ a_buf, const int* __restrict__ w2,
    const int* __restrict__ w2s, const int* __restrict__ counts,
    const int* __restrict__ offsets, ushort* __restrict__ ye, int yb, int yw)
{
  const int e  = blockIdx.x;
  const int n0 = yb + (blockIdx.y << 6);
  const int m0 = blockIdx.z << 7;
  const int cnt = counts[e];
  if (m0 >= cnt) return;
  const int NIT = IDIM / 64;   // 12, even

  __shared__ __align__(16) ushort Bsh[2][64*LDB];

  const int tid = threadIdx.x;
  const int wv = tid >> 6, l = tid & 63, l16 = l & 15, q = l >> 4;
  const int obase = offsets[e];

  const ushort* arow[2];
#pragma unroll
  for (int i = 0; i < 2; i++) {
    int gm = m0 + wv*32 + i*16 + l16;
    int rowc = (gm < cnt) ? gm : 0;
    arow[i] = a_buf + (size_t)(obase + rowc)*IDIM + q*8;
  }

  const int rb = tid >> 2, hq = tid & 3;
  const int* wrow = w2 + ((size_t)e*DDIM + n0 + rb)*(IDIM/2) + hq*8;
  const int* srow = w2s + ((size_t)e*DDIM + n0 + rb)*(IDIM/32) + (hq >> 1);
  const int bdst = rb*LDB + hq*16;

  f32x4 acc[2][4];
#pragma unroll
  for (int i = 0; i < 2; i++)
#pragma unroll
    for (int j = 0; j < 4; j++) acc[i][j] = (f32x4){0.f,0.f,0.f,0.f};

  bf16x8 aA[2][2], aB[2][2];
  int4 wA0, wA1, wB0, wB1; uint32_t SA, SB;

  {
    int4 t0 = *(const int4*)(wrow);
    int4 t1 = *(const int4*)(wrow + 4);
    uint32_t S = (((uint32_t)srow[0]) - 1u) << 1;
    deq8(t0, t1, S, &Bsh[0][bdst]);
  }
#pragma unroll
  for (int i = 0; i < 2; i++)
#pragma unroll
    for (int s = 0; s < 2; s++)
      aA[i][s] = *(const bf16x8*)(arow[i] + s*32);
  wA0 = *(const int4*)(wrow + 32); wA1 = *(const int4*)(wrow + 36);
  SA  = (((uint32_t)srow[2]) - 1u) << 1;
#pragma unroll
  for (int i = 0; i < 2; i++)
#pragma unroll
    for (int s = 0; s < 2; s++)
      aB[i][s] = *(const bf16x8*)(arow[i] + 64 + s*32);
  __syncthreads();

  for (int t = 0; t < NIT; t += 2) {
    int t2 = t + 2 < NIT ? t + 2 : NIT - 1;
    wB0 = *(const int4*)(wrow + t2*32);
    wB1 = *(const int4*)(wrow + t2*32 + 4);
    SB  = (((uint32_t)srow[t2*2]) - 1u) << 1;
#pragma unroll
    for (int s = 0; s < 2; s++) {
      bf16x8 bfr[4];
#pragma unroll
      for (int j = 0; j < 4; j++)
        bfr[j] = *(const bf16x8*)&Bsh[0][(j*16 + l16)*LDB + s*32 + q*8];
#pragma unroll
      for (int i = 0; i < 2; i++)
#pragma unroll
        for (int j = 0; j < 4; j++)
          acc[i][j] = __builtin_amdgcn_mfma_f32_16x16x32_bf16(aA[i][s], bfr[j], acc[i][j], 0, 0, 0);
    }
    deq8(wA0, wA1, SA, &Bsh[1][bdst]);
#pragma unroll
    for (int i = 0; i < 2; i++)
#pragma unroll
      for (int s = 0; s < 2; s++)
        aA[i][s] = *(const bf16x8*)(arow[i] + t2*64 + s*32);
    __syncthreads();

    int t3 = t + 3 < NIT ? t + 3 : NIT - 1;
    wA0 = *(const int4*)(wrow + t3*32);
    wA1 = *(const int4*)(wrow + t3*32 + 4);
    SA  = (((uint32_t)srow[t3*2]) - 1u) << 1;
#pragma unroll
    for (int s = 0; s < 2; s++) {
      bf16x8 bfr[4];
#pragma unroll
      for (int j = 0; j < 4; j++)
        bfr[j] = *(const bf16x8*)&Bsh[1][(j*16 + l16)*LDB + s*32 + q*8];
#pragma unroll
      for (int i = 0; i < 2; i++)
#pragma unroll
        for (int j = 0; j < 4; j++)
          acc[i][j] = __builtin_amdgcn_mfma_f32_16x16x32_bf16(aB[i][s], bfr[j], acc[i][j], 0, 0, 0);
    }
    deq8(wB0, wB1, SB, &Bsh[0][bdst]);
#pragma unroll
    for (int i = 0; i < 2; i++)
#pragma unroll
      for (int s = 0; s < 2; s++)
        aB[i][s] = *(const bf16x8*)(arow[i] + t3*64 + s*32);
    __syncthreads();
  }

#pragma unroll
  for (int i = 0; i < 2; i++) {
#pragma unroll
    for (int r = 0; r < 4; r++) {
      int mrow = wv*32 + i*16 + q*4 + r;
      int gm = m0 + mrow;
      if (gm < cnt) {
        ushort* dst = ye + (size_t)(obase + gm)*yw + (n0 - yb) + l16;
#pragma unroll
        for (int j = 0; j < 4; j++) {
          uint32_t bb = __float_as_uint(acc[i][j][r]);
          bb += 0x7FFFu + ((bb >> 16) & 1u);
          dst[j*16] = (ushort)(bb >> 16);
        }
      }
    }
  }
}

// ---------- combine (one D-slice): out[t, yb+c] = sum of routed ye rows ----------
__global__ void combine_kernel(const ushort* __restrict__ ye, const int* __restrict__ offsets,
                               const ushort* __restrict__ tpp, const int* __restrict__ tpn,
                               float* __restrict__ out, int yb, int yw) {
  int t = blockIdx.x;
  int np = tpn[t];
  int rows[TOPK];
#pragma unroll
  for (int j = 0; j < TOPK; j++) {
    if (j < np) {
      uint32_t v = tpp[t*TOPK + j];
      rows[j] = offsets[v >> 12] + (int)(v & 0xFFFu);
    } else rows[j] = -1;
  }
  for (int c = threadIdx.x; c < yw; c += 256) {
    float s = 0.f;
#pragma unroll
    for (int j = 0; j < TOPK; j++)
      if (rows[j] >= 0)
        s += __uint_as_float(((uint32_t)ye[(size_t)rows[j]*yw + c]) << 16);
    out[(size_t)t*DDIM + yb + c] = s;
  }
}

extern "C" void kernel_launch(void* const* d_in, const int* in_sizes, int n_in,
                              void* d_out, int out_size, void* d_ws, size_t ws_size,
                              hipStream_t stream)
{
  const float* x    = (const float*)d_in[0];
  const float* tw   = (const float*)d_in[1];
  const int*   tids = (const int*)d_in[2];
  const int*   w13  = (const int*)d_in[3];
  const int*   w13s = (const int*)d_in[4];
  const int*   w2   = (const int*)d_in[5];
  const int*   w2s  = (const int*)d_in[6];
  float* out = (float*)d_out;

  char* ws = (char*)d_ws;
  size_t off = 0;
  auto alloc = [&](size_t bytes) { void* p = ws + off; off = (off + bytes + 255) & ~(size_t)255; return p; };
  float* combs   = (float*)alloc((size_t)NEXP*T_TOK*4);
  short* lists   = (short*)alloc((size_t)NEXP*T_TOK*2);
  ushort* tpp    = (ushort*)alloc((size_t)T_TOK*TOPK*2);
  int*   tpn     = (int*)alloc((size_t)T_TOK*4);
  int*   counts  = (int*)alloc(64*4);
  int*   offsets = (int*)alloc(64*4);
  ushort* a_buf  = (ushort*)alloc((size_t)T_TOK*TOPK*IDIM*2);   // 6.29 MB
  ushort* ye     = (ushort*)(ws + off);
  ushort* xq     = ye;   // alias: xq (2.1 MB) dead before gemm2 writes ye

  size_t ye_full = (size_t)T_TOK*TOPK*DDIM*2;                   // 16.8 MB
  int nslice = (ws_size >= off + ye_full) ? 1 : 2;              // runtime-constant
  int yw = DDIM / nslice;

  qdq_route_kernel<<<(T_TOK*DDIM)/2048 + 1, 512, 0, stream>>>(
      x, xq, tids, tw, counts, offsets, lists, combs, tpp, tpn);
  gemm1_kernel<<<dim3(NEXP, IDIM/32, 4), 256, 0, stream>>>(
      xq, w13, w13s, counts, offsets, lists, combs, a_buf);
  for (int p = 0; p < nslice; p++) {
    gemm2_kernel<<<dim3(NEXP, yw/64, 4), 256, 0, stream>>>(
        a_buf, w2, w2s, counts, offsets, ye, p*yw, yw);
    combine_kernel<<<T_TOK, 256, 0, stream>>>(ye, offsets, tpp, tpn, out, p*yw, yw);
  }
}